// Round 10
// baseline (56.378 us; speedup 1.0000x reference)
//
#include <hip/hip_runtime.h>
#include <stdint.h>

typedef __fp16 fp16x2 __attribute__((ext_vector_type(2)));
typedef _Float16 half4 __attribute__((ext_vector_type(4)));
typedef _Float16 half8 __attribute__((ext_vector_type(8)));
typedef float f32x4 __attribute__((ext_vector_type(4)));

#define NS 4096
#define NTOT 8192
#define DD 256
#define NBLK2 528   // 136 SS tri + 136 TT tri + 256 ST (256x256 tiles)

// X16 "tiled4" layout: addr(r,k) = (r>>4)*4096 + (k>>3)*128 + (r&15)*8 + (k&7)
// -> each (16-row, 64-col) K-tile slice of a 16-row group is one contiguous
// 2KB block; staging is wave-uniform base + lane*16B, LDS fragment-ordered.

// workspace layout (bytes)
#define OFF_X16   0                        // 8192*256*2 = 4 MB fp16 (tiled4)
#define OFF_SQ    (4*1024*1024)            // 8192 floats
#define OFF_COLP  (OFF_SQ + 32*1024)       // 256*256 floats = 256 KB
#define OFF_BP    (OFF_COLP + 256*1024)    // 528 floats
#define OFF_SCAL  (OFF_BP + 8320)          // 1 float (exp2 scale)

// ---------------------------------------------------------------- K1: prep
__global__ __launch_bounds__(256) void mmd_prep(const float* __restrict__ S,
                                                const float* __restrict__ T,
                                                _Float16* __restrict__ X16,
                                                float* __restrict__ sq,
                                                float* __restrict__ colpart) {
    __shared__ _Float16 tile[16][264];     // +8 halves pad: conflict-free reorder
    __shared__ float cl[4][256];
    const int b = blockIdx.x, tid = threadIdx.x;
    const int lane = tid & 63, w = tid >> 6;
    f32x4 cacc = {0.f, 0.f, 0.f, 0.f};
    #pragma unroll
    for (int h = 0; h < 2; ++h) {
        #pragma unroll
        for (int rr = 0; rr < 4; ++rr) {
            const int row = b * 32 + h * 16 + w * 4 + rr;   // wave-uniform
            const float* src = (row < NS) ? (S + (size_t)row * DD)
                                          : (T + (size_t)(row - NS) * DD);
            const f32x4 v = *(const f32x4*)(src + lane * 4);
            cacc += v;
            float vv = v.x * v.x + v.y * v.y + v.z * v.z + v.w * v.w;
            half4 hx = { (_Float16)v.x, (_Float16)v.y, (_Float16)v.z, (_Float16)v.w };
            *(half4*)&tile[w * 4 + rr][lane * 4] = hx;
            #pragma unroll
            for (int off = 32; off; off >>= 1) vv += __shfl_down(vv, off);
            if (lane == 0) sq[row] = vv;
        }
        __syncthreads();
        _Float16* dst = X16 + (size_t)(b * 2 + h) * 4096;
        #pragma unroll
        for (int q = 0; q < 2; ++q) {
            const int c = q * 256 + tid;                    // chunk = kc*16+rl
            *(half8*)(dst + c * 8) = *(const half8*)&tile[c & 15][(c >> 4) * 8];
        }
        __syncthreads();
    }
    *(f32x4*)&cl[w][lane * 4] = cacc;
    __syncthreads();
    colpart[b * 256 + tid] = cl[0][tid] + cl[1][tid] + cl[2][tid] + cl[3][tid];
}

// ---------------------------------------------------------------- K2: bandwidth
__global__ __launch_bounds__(1024) void mmd_bw(const float* __restrict__ colpart,
                                               const float* __restrict__ sq,
                                               float* __restrict__ scal) {
    __shared__ float cpart[4][256];
    __shared__ double sd[16], sf[16];
    const int t = threadIdx.x;
    const int c = t & 255, g = t >> 8;
    float cs = 0.0f;
    #pragma unroll
    for (int b = 0; b < 64; ++b) cs += colpart[((g * 64 + b) << 8) | c];
    cpart[g][c] = cs;
    const f32x4 q0 = *(const f32x4*)(sq + t * 8);
    const f32x4 q1 = *(const f32x4*)(sq + t * 8 + 4);
    double qd = (double)(q0.x + q0.y + q0.z + q0.w) +
                (double)(q1.x + q1.y + q1.z + q1.w);
    __syncthreads();
    double s2 = 0.0;
    if (g == 0) {
        const double tot = (double)cpart[0][c] + cpart[1][c] +
                           cpart[2][c] + cpart[3][c];
        s2 = tot * tot;
    }
    const int lane = t & 63, w = t >> 6;
    #pragma unroll
    for (int off = 32; off; off >>= 1) {
        s2 += __shfl_down(s2, off);
        qd += __shfl_down(qd, off);
    }
    if (lane == 0) { sd[w] = s2; sf[w] = qd; }
    __syncthreads();
    if (t == 0) {
        double s2t = 0.0, qt = 0.0;
        #pragma unroll
        for (int i = 0; i < 16; ++i) { s2t += sd[i]; qt += sf[i]; }
        const double n = (double)NTOT;
        const double sumd2 = 2.0 * n * qt - 2.0 * s2t;
        double bwv = sumd2 / (n * n - n);
        bwv = bwv / 4.0;   // KERNEL_MUL^(KERNEL_NUM//2) = 2^2
        scal[0] = (float)(1.0 / (16.0 * bwv * 0.6931471805599453));
    }
}

// ---------------------------------------------------------------- K3: main GEMM+kernel
// 256x256 tile, 8 waves (2M x 4N), BK=64 x 4 K-tiles, 128KB double-buffered
// fragment-ordered LDS. Per K-tile: 4 barrier-clustered phases of 16 MFMA
// (T3/T5); stage(t+1) issues in phase 0 of tile t, vmcnt(0)+barrier only at
// the tile boundary (~4 phases after issue -> no fresh drain). B-fragments
// register-resident per K-tile. pk-fp16 exp epilogue (r6-proven math).
__global__ __launch_bounds__(512, 2) void mmd_main(const _Float16* __restrict__ X16,
                                                   const float* __restrict__ sq,
                                                   const float* __restrict__ scal,
                                                   float* __restrict__ blockpart) {
    __shared__ _Float16 As[2][16384];      // 2 x 32 KB
    __shared__ _Float16 Bs[2][16384];
    __shared__ float wsum[8];

    // T1: XCD swizzle (528 % 8 == 0 -> bijective simple form)
    const int bid = (blockIdx.x % 8) * (NBLK2 / 8) + blockIdx.x / 8;
    int br, bc;
    float wfac;
    if (bid < 272) {
        int t = bid, base = 0;
        if (t >= 136) { t -= 136; base = 16; }
        int i = (int)((sqrtf(8.0f * (float)t + 1.0f) - 1.0f) * 0.5f);
        while ((i + 1) * (i + 2) / 2 <= t) ++i;
        while (i * (i + 1) / 2 > t) --i;
        const int j = t - i * (i + 1) / 2;
        br = base + i; bc = base + j;
        wfac = (i == j) ? 1.0f : 2.0f;   // off-diag tile counts for (i,j) and (j,i)
    } else {
        const int t = bid - 272;
        br = t >> 4; bc = 16 + (t & 15);
        wfac = -2.0f;                    // loss has -2*xy
    }
    const int row0 = br * 256, col0 = bc * 256;
    const int tid = threadIdx.x;
    const int lane = tid & 63;
    const int w = tid >> 6;
    const int wr2 = w >> 2, wc4 = w & 3;   // wave tile: rows [wr2*128,+128) x cols [wc4*64,+64)
    const int rA = lane & 15, hi = lane >> 4;
    const int lof = hi * 128 + rA * 8;     // fragment offset within a 1024-elem region

    const _Float16* Ag = X16 + (size_t)(row0 >> 4) * 4096;
    const _Float16* Bg = X16 + (size_t)(col0 >> 4) * 4096;

    // stage one 256x64 A+B K-tile pair into slot s (8 gload_lds per thread)
    auto STAGE = [&](int s, int kt) {
        #pragma unroll
        for (int i = 0; i < 4; ++i) {
            const int c = i * 512 + tid;          // 0..2047 chunks of 16B
            const int rg = c >> 7, of = c & 127;  // 16-row group, 16B chunk in 2KB
            const _Float16* ga = Ag + (size_t)rg * 4096 + kt * 1024 + of * 8;
            const _Float16* gb = Bg + (size_t)rg * 4096 + kt * 1024 + of * 8;
            __builtin_amdgcn_global_load_lds(
                (const __attribute__((address_space(1))) uint32_t*)ga,
                (__attribute__((address_space(3))) uint32_t*)&As[s][c * 8], 16, 0, 0);
            __builtin_amdgcn_global_load_lds(
                (const __attribute__((address_space(1))) uint32_t*)gb,
                (__attribute__((address_space(3))) uint32_t*)&Bs[s][c * 8], 16, 0, 0);
        }
    };

    f32x4 acc[8][4] = {};                  // 128 VGPR accumulator
    STAGE(0, 0);
    asm volatile("s_waitcnt vmcnt(0)" ::: "memory");
    __builtin_amdgcn_s_barrier();

    #pragma unroll
    for (int kt = 0; kt < 4; ++kt) {
        const int cur = kt & 1;
        if (kt < 3) STAGE(cur ^ 1, kt + 1);       // prefetch next K-tile (other buf)
        half8 b[4][2];
        #pragma unroll
        for (int nf = 0; nf < 4; ++nf)
            #pragma unroll
            for (int kk = 0; kk < 2; ++kk)
                b[nf][kk] = *(const half8*)&Bs[cur][(wc4 * 4 + nf) * 1024
                                                    + kk * 512 + lof];
        #pragma unroll
        for (int ph = 0; ph < 4; ++ph) {           // phase = one m-pair quadrant
            half8 a[2][2];
            #pragma unroll
            for (int mi = 0; mi < 2; ++mi)
                #pragma unroll
                for (int kk = 0; kk < 2; ++kk)
                    a[mi][kk] = *(const half8*)&As[cur][(wr2 * 8 + ph * 2 + mi) * 1024
                                                        + kk * 512 + lof];
            __builtin_amdgcn_s_setprio(1);
            #pragma unroll
            for (int mi = 0; mi < 2; ++mi)
                #pragma unroll
                for (int nf = 0; nf < 4; ++nf)
                    #pragma unroll
                    for (int kk = 0; kk < 2; ++kk)
                        acc[ph * 2 + mi][nf] = __builtin_amdgcn_mfma_f32_16x16x32_f16(
                            a[mi][kk], b[nf][kk], acc[ph * 2 + mi][nf], 0, 0, 0);
            __builtin_amdgcn_s_setprio(0);
            if (ph < 3) __builtin_amdgcn_s_barrier();   // cluster waves per phase
        }
        if (kt < 3) {
            asm volatile("s_waitcnt vmcnt(0)" ::: "memory");  // tile t+1 landed (issued 4 phases ago)
            __builtin_amdgcn_s_barrier();
        }
    }

    // epilogue: e4 = exp2(-d2*cl2); kernel sum = e+e^2+e^4+e^8+e^16 (pk-fp16).
    // x = g*2cl2 + (sip+sjp); clamp x<=0 (== d2>=0).
    const float cl2 = scal[0];
    const float c2  = 2.0f * cl2;
    float sjp[4];
    #pragma unroll
    for (int nf = 0; nf < 4; ++nf)
        sjp[nf] = -cl2 * sq[col0 + wc4 * 64 + nf * 16 + rA];

    float part = 0.0f;
    const fp16x2 one2 = {(__fp16)1.0f, (__fp16)1.0f};
    #pragma unroll
    for (int mf = 0; mf < 8; ++mf) {
        float sip[4];
        #pragma unroll
        for (int r = 0; r < 4; ++r)
            sip[r] = -cl2 * sq[row0 + wr2 * 128 + mf * 16 + hi * 4 + r];
        #pragma unroll
        for (int nf = 0; nf < 4; ++nf)
            #pragma unroll
            for (int rp = 0; rp < 2; ++rp) {
                const float x0 = fminf(fmaf(acc[mf][nf][2 * rp],     c2,
                                            sip[2 * rp]     + sjp[nf]), 0.0f);
                const float x1 = fminf(fmaf(acc[mf][nf][2 * rp + 1], c2,
                                            sip[2 * rp + 1] + sjp[nf]), 0.0f);
#if __has_builtin(__builtin_amdgcn_exp2f)
                const float e0 = __builtin_amdgcn_exp2f(x0);
                const float e1 = __builtin_amdgcn_exp2f(x1);
#else
                const float e0 = exp2f(x0);
                const float e1 = exp2f(x1);
#endif
                fp16x2 h  = __builtin_amdgcn_cvt_pkrtz(e0, e1);
                fp16x2 p2 = h * h;           // e^2
                fp16x2 ks = h + p2;
                p2 = p2 * p2; ks += p2;      // e^4
                p2 = p2 * p2; ks += p2;      // e^8
                p2 = p2 * p2; ks += p2;      // e^16
#if __has_builtin(__builtin_amdgcn_fdot2)
                part = __builtin_amdgcn_fdot2(ks, one2, part, false);
#else
                part += (float)ks.x + (float)ks.y;
#endif
            }
    }

    #pragma unroll
    for (int off = 32; off > 0; off >>= 1) part += __shfl_down(part, off);
    if (lane == 0) wsum[w] = part;
    __syncthreads();
    if (tid == 0) {
        float s = 0.0f;
        #pragma unroll
        for (int i = 0; i < 8; ++i) s += wsum[i];
        blockpart[bid] = s * wfac;
    }
}

// ---------------------------------------------------------------- K4: final reduce
__global__ __launch_bounds__(512) void mmd_final(const float* __restrict__ blockpart,
                                                 float* __restrict__ out) {
    const int t = threadIdx.x;
    double acc = (double)blockpart[t];
    if (t < NBLK2 - 512) acc += (double)blockpart[t + 512];
    #pragma unroll
    for (int off = 32; off > 0; off >>= 1) acc += __shfl_down(acc, off);
    __shared__ double sd[8];
    const int lane = t & 63, w = t >> 6;
    if (lane == 0) sd[w] = acc;
    __syncthreads();
    if (t == 0) {
        double tot = 0.0;
        #pragma unroll
        for (int i = 0; i < 8; ++i) tot += sd[i];
        tot /= ((double)NS * (double)NS);
        out[0] = (float)fmax(tot, 0.0);
    }
}

// ---------------------------------------------------------------- launch
extern "C" void kernel_launch(void* const* d_in, const int* in_sizes, int n_in,
                              void* d_out, int out_size, void* d_ws, size_t ws_size,
                              hipStream_t stream) {
    const float* S = (const float*)d_in[0];
    const float* T = (const float*)d_in[1];
    char* ws = (char*)d_ws;
    _Float16* X16   = (_Float16*)(ws + OFF_X16);
    float* sq       = (float*)(ws + OFF_SQ);
    float* colpart  = (float*)(ws + OFF_COLP);
    float* blockpart= (float*)(ws + OFF_BP);
    float* scal     = (float*)(ws + OFF_SCAL);

    mmd_prep<<<256, 256, 0, stream>>>(S, T, X16, sq, colpart);
    mmd_bw<<<1, 1024, 0, stream>>>(colpart, sq, scal);
    mmd_main<<<NBLK2, 512, 0, stream>>>(X16, sq, scal, blockpart);
    mmd_final<<<1, 512, 0, stream>>>(blockpart, (float*)d_out);
}